// Round 4
// baseline (189.160 us; speedup 1.0000x reference)
//
#include <hip/hip_runtime.h>
#include <hip/hip_bf16.h>
#include <stdint.h>

// Problem constants
#define NB   64          // batch*windows
#define NTOK 196         // tokens per window
#define NH   32          // heads
#define HD   4           // head dim
#define CE   128         // embed
#define NM   38416       // 196*196

typedef __bf16 bf16x8 __attribute__((ext_vector_type(8)));
typedef float  f32x4  __attribute__((ext_vector_type(4)));

#define QSCALE 0.7213475204444817f   /* 0.5 * log2(e) */
#define LOG2E  1.4426950408889634f

__device__ __forceinline__ float u2f(unsigned short u) {
    union { unsigned int i; float f; } z;
    z.i = ((unsigned int)u) << 16;
    return z.f;
}
__device__ __forceinline__ unsigned short f2u(float f) {
    union { float f; unsigned int i; } z; z.f = f;
    unsigned int x = z.i;
    return (unsigned short)((x + 0x7fffu + ((x >> 16) & 1u)) >> 16); // RNE
}

// ---------------------------------------------------------------------------
// Kernel 1: QKV GEMM via MFMA bf16. Writes Qb/Kb packed bf16 [b,h][n][br*4+d]
// (Q pre-scaled by 0.5*log2e) and V bf16 [b][2H][n][d] for the fuse stage.
// ---------------------------------------------------------------------------
extern "C" __global__ __launch_bounds__(256) void qkv_gemm(
    const float* __restrict__ x1,
    const float* __restrict__ x2,
    const float* __restrict__ qkvw,
    unsigned short* __restrict__ Qb, unsigned short* __restrict__ Kb,
    unsigned short* __restrict__ V)
{
    __shared__ alignas(16) unsigned short AT[64][136];
    __shared__ alignas(16) unsigned short BT[64][136];
    const int tid = threadIdx.x;
    const int r0 = blockIdx.x * 64;     // token rows (both branches)
    const int j0 = blockIdx.y * 64;     // cols of 384

    for (int idx = tid; idx < 2048; idx += 256) {
        int row = idx >> 5, k0 = (idx & 31) << 2;
        int r = r0 + row;
        const float* xp = (r >= 12544) ? x2 : x1;
        int rem = r - ((r >= 12544) ? 12544 : 0);
        float4 v = *(const float4*)&xp[rem * 128 + k0];
        ushort4 u; u.x = f2u(v.x); u.y = f2u(v.y); u.z = f2u(v.z); u.w = f2u(v.w);
        *(ushort4*)&AT[row][k0] = u;
    }
    for (int idx = tid; idx < 2048; idx += 256) {
        int row = idx >> 5, k0 = (idx & 31) << 2;
        float4 v = *(const float4*)&qkvw[(j0 + row) * 128 + k0];
        ushort4 u; u.x = f2u(v.x); u.y = f2u(v.y); u.z = f2u(v.z); u.w = f2u(v.w);
        *(ushort4*)&BT[row][k0] = u;
    }
    __syncthreads();

    const int lane = tid & 63, w = tid >> 6;
    const int wm = (w >> 1) * 32, wn = (w & 1) * 32;
    const int quad = lane >> 4, tcol = lane & 15;

    f32x4 acc[2][2] = {};
#pragma unroll
    for (int ks = 0; ks < 4; ++ks) {
        int k0 = ks * 32 + quad * 8;
        bf16x8 a0 = *(const bf16x8*)&AT[wm + tcol][k0];
        bf16x8 a1 = *(const bf16x8*)&AT[wm + 16 + tcol][k0];
        bf16x8 b0 = *(const bf16x8*)&BT[wn + tcol][k0];
        bf16x8 b1 = *(const bf16x8*)&BT[wn + 16 + tcol][k0];
        acc[0][0] = __builtin_amdgcn_mfma_f32_16x16x32_bf16(a0, b0, acc[0][0], 0, 0, 0);
        acc[0][1] = __builtin_amdgcn_mfma_f32_16x16x32_bf16(a0, b1, acc[0][1], 0, 0, 0);
        acc[1][0] = __builtin_amdgcn_mfma_f32_16x16x32_bf16(a1, b0, acc[1][0], 0, 0, 0);
        acc[1][1] = __builtin_amdgcn_mfma_f32_16x16x32_bf16(a1, b1, acc[1][1], 0, 0, 0);
    }

#pragma unroll
    for (int mi = 0; mi < 2; ++mi) {
#pragma unroll
        for (int ni = 0; ni < 2; ++ni) {
            int jglob = j0 + wn + ni * 16 + tcol;
            int sel = jglob >> 7;            // 0=q 1=k 2=v
            int jj = jglob & 127;
            int h = jj >> 2, dd = jj & 3;
#pragma unroll
            for (int reg = 0; reg < 4; ++reg) {
                int r = r0 + wm + mi * 16 + quad * 4 + reg;
                int branch = (r >= 12544) ? 1 : 0;
                int rem = r - branch * 12544;
                int b = rem / 196;
                int n = rem - b * 196;
                float v = acc[mi][ni][reg];
                if (sel == 0) {
                    Qb[((b * 32 + h) * 196 + n) * 8 + branch * 4 + dd] = f2u(v * QSCALE);
                } else if (sel == 1) {
                    Kb[((b * 32 + h) * 196 + n) * 8 + branch * 4 + dd] = f2u(v);
                } else {
                    V[(b * 64 + branch * 32 + h) * 784 + n * 4 + dd] = f2u(v);
                }
            }
        }
    }
}

// ---------------------------------------------------------------------------
// Kernel 2: bias in MFMA C-fragment order: biasM[h][qt 13][nt 14][lane 64][reg 4]
// bf16, pre-scaled by log2e; -inf (0xFF80) in q/key padding (masks softmax).
// ---------------------------------------------------------------------------
extern "C" __global__ __launch_bounds__(256) void bias_build(
    const int* __restrict__ rel_idx, const float* __restrict__ rpb,
    unsigned short* __restrict__ biasM)
{
    const int qt = blockIdx.x;   // 0..12
    const int h  = blockIdx.y;   // 0..31
    const int tid = threadIdx.x, lane = tid & 63, wv = tid >> 6;
    const int quad = lane >> 4, tc = lane & 15;
    for (int nt = wv; nt < 14; nt += 4) {
        union { uint2 v; unsigned short s[4]; } e;
#pragma unroll
        for (int r = 0; r < 4; ++r) {
            int q = qt * 16 + quad * 4 + r;
            int key = nt * 16 + tc;
            unsigned short u = 0xFF80;  // -inf bf16
            if (q < 196 && key < 196) {
                int idx = rel_idx[q * 196 + key];
                u = f2u(rpb[idx * 32 + h] * LOG2E);
            }
            e.s[r] = u;
        }
        *(uint2*)(biasM + (((h * 13 + qt) * 14 + nt) * 64 + lane) * 4) = e.v;
    }
}

// ---------------------------------------------------------------------------
// Kernel 3: conv-gated value fusion + InstanceNorm + sigmoid(relu). (unchanged)
// ---------------------------------------------------------------------------
__device__ __forceinline__ float block_sum(float v, float* red, int tid) {
#pragma unroll
    for (int off = 32; off > 0; off >>= 1) v += __shfl_down(v, off);
    __syncthreads();
    if ((tid & 63) == 0) red[tid >> 6] = v;
    __syncthreads();
    return red[0] + red[1] + red[2] + red[3];
}

__device__ __forceinline__ float act_sig_relu(float x) {
    return x > 0.f ? __fdividef(1.f, 1.f + __expf(-x)) : 0.5f;
}

extern "C" __global__ __launch_bounds__(256) void fuse_kernel(
    const unsigned short* __restrict__ V,
    const float* __restrict__ fuse_w,
    const float* __restrict__ fuse_b,
    float* __restrict__ Vf)
{
    const int b = blockIdx.x, o0 = blockIdx.y * 2;
    const int tid = threadIdx.x;
    __shared__ float fws[2][64];
    __shared__ float red[4];
    if (tid < 128) fws[tid >> 6][tid & 63] = fuse_w[(o0 + (tid >> 6)) * 64 + (tid & 63)];
    __syncthreads();

    const unsigned short* Vb = V + b * 64 * 784;
    float a0[3] = {0.f, 0.f, 0.f}, a1[3] = {0.f, 0.f, 0.f};
    float t0 = 0.f, t1 = 0.f;
    const bool tail = tid < 16;
    for (int c = 0; c < 64; ++c) {
        float w0 = fws[0][c], w1 = fws[1][c];
        const unsigned short* Vc = Vb + c * 784;
#pragma unroll
        for (int k = 0; k < 3; ++k) {
            float x = u2f(Vc[tid + 256 * k]);
            a0[k] = fmaf(w0, x, a0[k]);
            a1[k] = fmaf(w1, x, a1[k]);
        }
        if (tail) {
            float x = u2f(Vc[tid + 768]);
            t0 = fmaf(w0, x, t0);
            t1 = fmaf(w1, x, t1);
        }
    }
    float fb0 = fuse_b[o0], fb1 = fuse_b[o0 + 1];
#pragma unroll
    for (int k = 0; k < 3; ++k) { a0[k] += fb0; a1[k] += fb1; }
    t0 += fb0; t1 += fb1;

    float s0 = a0[0] + a0[1] + a0[2] + (tail ? t0 : 0.f);
    float q0 = a0[0]*a0[0] + a0[1]*a0[1] + a0[2]*a0[2] + (tail ? t0*t0 : 0.f);
    float s1 = a1[0] + a1[1] + a1[2] + (tail ? t1 : 0.f);
    float q1 = a1[0]*a1[0] + a1[1]*a1[1] + a1[2]*a1[2] + (tail ? t1*t1 : 0.f);

    float S0 = block_sum(s0, red, tid);
    float Q0 = block_sum(q0, red, tid);
    float S1 = block_sum(s1, red, tid);
    float Q1 = block_sum(q1, red, tid);

    const float inv = 1.0f / 784.0f;
    float mu0 = S0 * inv, mu1 = S1 * inv;
    float rs0 = rsqrtf(Q0 * inv - mu0 * mu0 + 1e-5f);
    float rs1 = rsqrtf(Q1 * inv - mu1 * mu1 + 1e-5f);

    float* out0 = Vf + (b * 32 + o0) * 784;
    float* out1 = out0 + 784;
#pragma unroll
    for (int k = 0; k < 3; ++k) {
        int e = tid + 256 * k;
        out0[e] = act_sig_relu((a0[k] - mu0) * rs0);
        out1[e] = act_sig_relu((a1[k] - mu1) * rs1);
    }
    if (tail) {
        out0[tid + 768] = act_sig_relu((t0 - mu0) * rs0);
        out1[tid + 768] = act_sig_relu((t1 - mu1) * rs1);
    }
}

// ---------------------------------------------------------------------------
// Kernel 4: MFMA attention. Block = (b,h), 4 waves; wave owns q-tiles
// {wv, wv+4, ...}. QK^T as 16x16x32 (K=8 useful, B-quads 1-3 zeroed); bias is
// the MFMA C-operand; P -> bf16 -> per-wave LDS strip -> PV MFMA with V^T
// staged [16][232] incl. a ones-column so rowsum falls out of the MFMA.
// ---------------------------------------------------------------------------
extern "C" __global__ __launch_bounds__(256) void attn_kernel(
    const unsigned short* __restrict__ Qb, const unsigned short* __restrict__ Kb,
    const float* __restrict__ Vf, const unsigned short* __restrict__ biasM,
    unsigned short* __restrict__ Ob)
{
    const int bh = blockIdx.x;
    const int b = bh >> 5, h = bh & 31;
    __shared__ alignas(16) unsigned short Qs[208][8];
    __shared__ alignas(16) unsigned short Ks[224][8];
    __shared__ alignas(16) unsigned short VT[16][232];
    __shared__ alignas(16) float PT[4][16][36];
    const int tid = threadIdx.x;

    // stage Q rows (zero-padded to 208) and K rows (to 224)
    const unsigned short* Qrow = Qb + bh * 196 * 8;
    const unsigned short* Krow = Kb + bh * 196 * 8;
    if (tid < 208) {
        uint4 z = {0, 0, 0, 0};
        uint4 v = (tid < 196) ? *(const uint4*)(Qrow + tid * 8) : z;
        *(uint4*)&Qs[tid][0] = v;
    }
    if (tid < 224) {
        uint4 z = {0, 0, 0, 0};
        uint4 v = (tid < 196) ? *(const uint4*)(Krow + tid * 8) : z;
        *(uint4*)&Ks[tid][0] = v;
    }
    // zero VT then fill transposed V + ones row
    {
        unsigned int* vtw = (unsigned int*)&VT[0][0];
        for (int i = tid; i < (16 * 232) / 2; i += 256) vtw[i] = 0u;
    }
    __syncthreads();
    if (tid < 196) {
        float4 vv = *(const float4*)(Vf + bh * 784 + tid * 4);
        VT[0][tid] = f2u(vv.x); VT[1][tid] = f2u(vv.y);
        VT[2][tid] = f2u(vv.z); VT[3][tid] = f2u(vv.w);
        VT[4][tid] = 0x3F80;   // 1.0 bf16
    }
    __syncthreads();

    const int lane = tid & 63, wv = tid >> 6;
    const int quad = lane >> 4, tc = lane & 15;
    float* myPT = &PT[wv][0][0];

    for (int qt = wv; qt < 13; qt += 4) {
        // Q A-frag: only quad 0's k-slice is real; quads 1-3 read finite junk
        // that gets multiplied by the zeroed K-frag quads -> 0.
        bf16x8 qf = *(const bf16x8*)&Qs[qt * 16 + tc][0];
        const unsigned short* bq = biasM + (unsigned)((h * 13 + qt) * 14) * 256;
        f32x4 Oacc = {};
#pragma unroll 1
        for (int kt = 0; kt < 7; ++kt) {
#pragma unroll
            for (int half = 0; half < 2; ++half) {
                int nt = kt * 2 + half;
                bf16x8 kf = {};
                if (quad == 0) kf = *(const bf16x8*)&Ks[nt * 16 + tc][0];
                uint2 bw = *(const uint2*)(bq + nt * 256 + lane * 4);
                f32x4 s;
                union { unsigned int u; float f; } c0, c1, c2, c3;
                c0.u = bw.x << 16; c1.u = bw.x & 0xffff0000u;
                c2.u = bw.y << 16; c3.u = bw.y & 0xffff0000u;
                s[0] = c0.f; s[1] = c1.f; s[2] = c2.f; s[3] = c3.f;
                s = __builtin_amdgcn_mfma_f32_16x16x32_bf16(qf, kf, s, 0, 0, 0);
                // P = exp2(s)  (log2e pre-folded into Q scale and bias)
                float p0 = exp2f(s[0]), p1 = exp2f(s[1]);
                float p2 = exp2f(s[2]), p3 = exp2f(s[3]);
                int col = half * 16 + tc;
                myPT[(quad * 4 + 0) * 36 + col] = p0;
                myPT[(quad * 4 + 1) * 36 + col] = p1;
                myPT[(quad * 4 + 2) * 36 + col] = p2;
                myPT[(quad * 4 + 3) * 36 + col] = p3;
            }
            // PV for this 32-key tile
            float4 pa = *(const float4*)&myPT[tc * 36 + quad * 8];
            float4 pb = *(const float4*)&myPT[tc * 36 + quad * 8 + 4];
            bf16x8 pf;
            pf[0] = (__bf16)pa.x; pf[1] = (__bf16)pa.y;
            pf[2] = (__bf16)pa.z; pf[3] = (__bf16)pa.w;
            pf[4] = (__bf16)pb.x; pf[5] = (__bf16)pb.y;
            pf[6] = (__bf16)pb.z; pf[7] = (__bf16)pb.w;
            bf16x8 vfr = *(const bf16x8*)&VT[tc][kt * 32 + quad * 8];
            Oacc = __builtin_amdgcn_mfma_f32_16x16x32_bf16(pf, vfr, Oacc, 0, 0, 0);
        }
        // rowsum lives in col 4 of the O C-frag
        int srcLane = quad * 16 + 4;
        float r0 = __shfl(Oacc[0], srcLane);
        float r1 = __shfl(Oacc[1], srcLane);
        float r2 = __shfl(Oacc[2], srcLane);
        float r3 = __shfl(Oacc[3], srcLane);
        if (tc < 4) {
            int qbase = qt * 16 + quad * 4;
            unsigned short* op = Ob + (b * 196 + qbase) * 128 + h * 4 + tc;
            if (qbase + 0 < 196) op[0 * 128] = f2u(Oacc[0] * __builtin_amdgcn_rcpf(r0));
            if (qbase + 1 < 196) op[1 * 128] = f2u(Oacc[1] * __builtin_amdgcn_rcpf(r1));
            if (qbase + 2 < 196) op[2 * 128] = f2u(Oacc[2] * __builtin_amdgcn_rcpf(r2));
            if (qbase + 3 < 196) op[3 * 128] = f2u(Oacc[3] * __builtin_amdgcn_rcpf(r3));
        }
    }
}

// ---------------------------------------------------------------------------
// Kernel 5: output projection via MFMA bf16. out = Ob @ projW^T + b (fp32 out)
// ---------------------------------------------------------------------------
extern "C" __global__ __launch_bounds__(256) void proj_kernel(
    const unsigned short* __restrict__ Ob, const float* __restrict__ projw,
    const float* __restrict__ projb, float* __restrict__ out)
{
    __shared__ alignas(16) unsigned short AT[64][136];
    __shared__ alignas(16) unsigned short BT[64][136];
    const int tid = threadIdx.x;
    const int r0 = blockIdx.x * 64;
    const int j0 = blockIdx.y * 64;

    for (int idx = tid; idx < 1024; idx += 256) {
        int row = idx >> 4, k0 = (idx & 15) << 3;
        *(uint4*)&AT[row][k0] = *(const uint4*)&Ob[(r0 + row) * 128 + k0];
    }
    for (int idx = tid; idx < 2048; idx += 256) {
        int row = idx >> 5, k0 = (idx & 31) << 2;
        float4 v = *(const float4*)&projw[(j0 + row) * 128 + k0];
        ushort4 u; u.x = f2u(v.x); u.y = f2u(v.y); u.z = f2u(v.z); u.w = f2u(v.w);
        *(ushort4*)&BT[row][k0] = u;
    }
    __syncthreads();

    const int lane = tid & 63, w = tid >> 6;
    const int wm = (w >> 1) * 32, wn = (w & 1) * 32;
    const int quad = lane >> 4, tcol = lane & 15;

    f32x4 acc[2][2] = {};
#pragma unroll
    for (int ks = 0; ks < 4; ++ks) {
        int k0 = ks * 32 + quad * 8;
        bf16x8 a0 = *(const bf16x8*)&AT[wm + tcol][k0];
        bf16x8 a1 = *(const bf16x8*)&AT[wm + 16 + tcol][k0];
        bf16x8 b0 = *(const bf16x8*)&BT[wn + tcol][k0];
        bf16x8 b1 = *(const bf16x8*)&BT[wn + 16 + tcol][k0];
        acc[0][0] = __builtin_amdgcn_mfma_f32_16x16x32_bf16(a0, b0, acc[0][0], 0, 0, 0);
        acc[0][1] = __builtin_amdgcn_mfma_f32_16x16x32_bf16(a0, b1, acc[0][1], 0, 0, 0);
        acc[1][0] = __builtin_amdgcn_mfma_f32_16x16x32_bf16(a1, b0, acc[1][0], 0, 0, 0);
        acc[1][1] = __builtin_amdgcn_mfma_f32_16x16x32_bf16(a1, b1, acc[1][1], 0, 0, 0);
    }

#pragma unroll
    for (int mi = 0; mi < 2; ++mi) {
#pragma unroll
        for (int ni = 0; ni < 2; ++ni) {
            int j = j0 + wn + ni * 16 + tcol;
            float pb = projb[j];
#pragma unroll
            for (int reg = 0; reg < 4; ++reg) {
                int r = r0 + wm + mi * 16 + quad * 4 + reg;
                out[r * 128 + j] = acc[mi][ni][reg] + pb;
            }
        }
    }
}

// ---------------------------------------------------------------------------
extern "C" void kernel_launch(void* const* d_in, const int* in_sizes, int n_in,
                              void* d_out, int out_size, void* d_ws, size_t ws_size,
                              hipStream_t stream)
{
    const float* x1    = (const float*)d_in[0];
    const float* x2    = (const float*)d_in[1];
    const float* qkvw  = (const float*)d_in[2];
    const float* projw = (const float*)d_in[3];
    const float* projb = (const float*)d_in[4];
    const float* rpb   = (const float*)d_in[5];
    const float* fw    = (const float*)d_in[6];
    const float* fb    = (const float*)d_in[7];
    const int*   rel   = (const int*)d_in[8];
    float* out = (float*)d_out;

    char* w = (char*)d_ws;
    unsigned short* Qb  = (unsigned short*)(w);              //  6,422,528 B
    unsigned short* Kb  = (unsigned short*)(w + 6422528);    //  6,422,528 B
    unsigned short* V   = (unsigned short*)(w + 12845056);   //  6,422,528 B
    float*          Vf  = (float*)(w + 19267584);            //  6,422,528 B
    unsigned short* bM  = (unsigned short*)(w + 25690112);   //  2,981,888 B
    unsigned short* Ob  = (unsigned short*)(w + 28672000);   //  3,211,264 B
    // total 31,883,264 bytes used

    qkv_gemm  <<<dim3(392, 6), dim3(256), 0, stream>>>(x1, x2, qkvw, Qb, Kb, V);
    bias_build<<<dim3(13, 32), dim3(256), 0, stream>>>(rel, rpb, bM);
    fuse_kernel<<<dim3(64, 16), dim3(256), 0, stream>>>(V, fw, fb, Vf);
    attn_kernel<<<dim3(2048),   dim3(256), 0, stream>>>(Qb, Kb, Vf, bM, Ob);
    proj_kernel<<<dim3(196, 2), dim3(256), 0, stream>>>(Ob, projw, projb, out);
}

// Round 5
// 174.014 us; speedup vs baseline: 1.0870x; 1.0870x over previous
//
#include <hip/hip_runtime.h>
#include <hip/hip_bf16.h>
#include <stdint.h>

// Problem constants
#define NB   64          // batch*windows
#define NTOK 196         // tokens per window
#define NH   32          // heads
#define HD   4           // head dim
#define CE   128         // embed
#define NM   38416       // 196*196

typedef __bf16 bf16x8 __attribute__((ext_vector_type(8)));
typedef float  f32x4  __attribute__((ext_vector_type(4)));

#define QSCALE 0.7213475204444817f   /* 0.5 * log2(e) */
#define LOG2E  1.4426950408889634f

__device__ __forceinline__ float u2f(unsigned short u) {
    union { unsigned int i; float f; } z;
    z.i = ((unsigned int)u) << 16;
    return z.f;
}
__device__ __forceinline__ unsigned short f2u(float f) {
    union { float f; unsigned int i; } z; z.f = f;
    unsigned int x = z.i;
    return (unsigned short)((x + 0x7fffu + ((x >> 16) & 1u)) >> 16); // RNE
}

// ---------------------------------------------------------------------------
// Kernel 1: QKV GEMM via MFMA bf16, computing C^T = W · X^T so the C-frag
// gives each lane all 4 head-dims of one head for one token -> uint2 stores.
// Qb/Kb packed bf16 [b,h][n][br*4+d] (Q pre-scaled), V bf16 [b][2H][n][d].
// ---------------------------------------------------------------------------
extern "C" __global__ __launch_bounds__(256) void qkv_gemm(
    const float* __restrict__ x1,
    const float* __restrict__ x2,
    const float* __restrict__ qkvw,
    unsigned short* __restrict__ Qb, unsigned short* __restrict__ Kb,
    unsigned short* __restrict__ V)
{
    __shared__ alignas(16) unsigned short AT[64][136];   // X rows (tokens)
    __shared__ alignas(16) unsigned short BT[64][136];   // W rows (j)
    const int tid = threadIdx.x;
    const int r0 = blockIdx.x * 64;     // token rows (both branches stacked)
    const int j0 = blockIdx.y * 64;     // cols of 384

    for (int idx = tid; idx < 2048; idx += 256) {
        int row = idx >> 5, k0 = (idx & 31) << 2;
        int r = r0 + row;
        const float* xp = (r >= 12544) ? x2 : x1;
        int rem = r - ((r >= 12544) ? 12544 : 0);
        float4 v = *(const float4*)&xp[rem * 128 + k0];
        ushort4 u; u.x = f2u(v.x); u.y = f2u(v.y); u.z = f2u(v.z); u.w = f2u(v.w);
        *(ushort4*)&AT[row][k0] = u;
    }
    for (int idx = tid; idx < 2048; idx += 256) {
        int row = idx >> 5, k0 = (idx & 31) << 2;
        float4 v = *(const float4*)&qkvw[(j0 + row) * 128 + k0];
        ushort4 u; u.x = f2u(v.x); u.y = f2u(v.y); u.z = f2u(v.z); u.w = f2u(v.w);
        *(ushort4*)&BT[row][k0] = u;
    }
    __syncthreads();

    const int lane = tid & 63, w = tid >> 6;
    const int wj = (w >> 1) * 32;    // j offset within block tile (M dim)
    const int wt = (w & 1) * 32;     // token offset (N dim)
    const int quad = lane >> 4, tc = lane & 15;

    f32x4 acc[2][2] = {};
#pragma unroll
    for (int ks = 0; ks < 4; ++ks) {
        int k0 = ks * 32 + quad * 8;
        bf16x8 a0 = *(const bf16x8*)&BT[wj + tc][k0];        // W rows (A: M=j)
        bf16x8 a1 = *(const bf16x8*)&BT[wj + 16 + tc][k0];
        bf16x8 b0 = *(const bf16x8*)&AT[wt + tc][k0];        // X rows (B: N=token)
        bf16x8 b1 = *(const bf16x8*)&AT[wt + 16 + tc][k0];
        acc[0][0] = __builtin_amdgcn_mfma_f32_16x16x32_bf16(a0, b0, acc[0][0], 0, 0, 0);
        acc[0][1] = __builtin_amdgcn_mfma_f32_16x16x32_bf16(a0, b1, acc[0][1], 0, 0, 0);
        acc[1][0] = __builtin_amdgcn_mfma_f32_16x16x32_bf16(a1, b0, acc[1][0], 0, 0, 0);
        acc[1][1] = __builtin_amdgcn_mfma_f32_16x16x32_bf16(a1, b1, acc[1][1], 0, 0, 0);
    }

    const int sel = j0 >> 7;   // 0=q 1=k 2=v, uniform per block
#pragma unroll
    for (int mi = 0; mi < 2; ++mi) {
        int jbase = (j0 + wj + mi * 16 + quad * 4) & 127;   // multiple of 4
        int hh = jbase >> 2;
#pragma unroll
        for (int ni = 0; ni < 2; ++ni) {
            int tok = r0 + wt + ni * 16 + tc;
            int branch = (tok >= 12544) ? 1 : 0;
            int rem = tok - branch * 12544;
            int bb = rem / 196;
            int nn = rem - bb * 196;
            union { uint2 v; unsigned short s[4]; } pk2;
            if (sel == 0) {
#pragma unroll
                for (int r = 0; r < 4; ++r) pk2.s[r] = f2u(acc[mi][ni][r] * QSCALE);
                *(uint2*)&Qb[((bb * 32 + hh) * 196 + nn) * 8 + branch * 4] = pk2.v;
            } else if (sel == 1) {
#pragma unroll
                for (int r = 0; r < 4; ++r) pk2.s[r] = f2u(acc[mi][ni][r]);
                *(uint2*)&Kb[((bb * 32 + hh) * 196 + nn) * 8 + branch * 4] = pk2.v;
            } else {
#pragma unroll
                for (int r = 0; r < 4; ++r) pk2.s[r] = f2u(acc[mi][ni][r]);
                *(uint2*)&V[(bb * 64 + branch * 32 + hh) * 784 + nn * 4] = pk2.v;
            }
        }
    }
}

// ---------------------------------------------------------------------------
// Kernel 2: bias in the S^T C-frag order: row=key=quad*4+reg, col=query=tc.
// biasM[h][qt 13][nt 14][lane 64][reg 4] bf16, pre-scaled by log2e;
// -inf (0xFF80) in padding (masks padded keys/queries in softmax).
// ---------------------------------------------------------------------------
extern "C" __global__ __launch_bounds__(256) void bias_build(
    const int* __restrict__ rel_idx, const float* __restrict__ rpb,
    unsigned short* __restrict__ biasM)
{
    const int qt = blockIdx.x;   // 0..12
    const int h  = blockIdx.y;   // 0..31
    const int tid = threadIdx.x, lane = tid & 63, wv = tid >> 6;
    const int quad = lane >> 4, tc = lane & 15;
    for (int nt = wv; nt < 14; nt += 4) {
        union { uint2 v; unsigned short s[4]; } e;
#pragma unroll
        for (int r = 0; r < 4; ++r) {
            int q   = qt * 16 + tc;              // query = col
            int key = nt * 16 + quad * 4 + r;    // key   = row
            unsigned short u = 0xFF80;  // -inf bf16
            if (q < 196 && key < 196) {
                int idx = rel_idx[q * 196 + key];
                u = f2u(rpb[idx * 32 + h] * LOG2E);
            }
            e.s[r] = u;
        }
        *(uint2*)(biasM + (((h * 13 + qt) * 14 + nt) * 64 + lane) * 4) = e.v;
    }
}

// ---------------------------------------------------------------------------
// Kernel 3: conv-gated value fusion + InstanceNorm + sigmoid(relu). (unchanged)
// ---------------------------------------------------------------------------
__device__ __forceinline__ float block_sum(float v, float* red, int tid) {
#pragma unroll
    for (int off = 32; off > 0; off >>= 1) v += __shfl_down(v, off);
    __syncthreads();
    if ((tid & 63) == 0) red[tid >> 6] = v;
    __syncthreads();
    return red[0] + red[1] + red[2] + red[3];
}

__device__ __forceinline__ float act_sig_relu(float x) {
    return x > 0.f ? __fdividef(1.f, 1.f + __expf(-x)) : 0.5f;
}

extern "C" __global__ __launch_bounds__(256) void fuse_kernel(
    const unsigned short* __restrict__ V,
    const float* __restrict__ fuse_w,
    const float* __restrict__ fuse_b,
    float* __restrict__ Vf)
{
    const int b = blockIdx.x, o0 = blockIdx.y * 2;
    const int tid = threadIdx.x;
    __shared__ float fws[2][64];
    __shared__ float red[4];
    if (tid < 128) fws[tid >> 6][tid & 63] = fuse_w[(o0 + (tid >> 6)) * 64 + (tid & 63)];
    __syncthreads();

    const unsigned short* Vb = V + b * 64 * 784;
    float a0[3] = {0.f, 0.f, 0.f}, a1[3] = {0.f, 0.f, 0.f};
    float t0 = 0.f, t1 = 0.f;
    const bool tail = tid < 16;
    for (int c = 0; c < 64; ++c) {
        float w0 = fws[0][c], w1 = fws[1][c];
        const unsigned short* Vc = Vb + c * 784;
#pragma unroll
        for (int k = 0; k < 3; ++k) {
            float x = u2f(Vc[tid + 256 * k]);
            a0[k] = fmaf(w0, x, a0[k]);
            a1[k] = fmaf(w1, x, a1[k]);
        }
        if (tail) {
            float x = u2f(Vc[tid + 768]);
            t0 = fmaf(w0, x, t0);
            t1 = fmaf(w1, x, t1);
        }
    }
    float fb0 = fuse_b[o0], fb1 = fuse_b[o0 + 1];
#pragma unroll
    for (int k = 0; k < 3; ++k) { a0[k] += fb0; a1[k] += fb1; }
    t0 += fb0; t1 += fb1;

    float s0 = a0[0] + a0[1] + a0[2] + (tail ? t0 : 0.f);
    float q0 = a0[0]*a0[0] + a0[1]*a0[1] + a0[2]*a0[2] + (tail ? t0*t0 : 0.f);
    float s1 = a1[0] + a1[1] + a1[2] + (tail ? t1 : 0.f);
    float q1 = a1[0]*a1[0] + a1[1]*a1[1] + a1[2]*a1[2] + (tail ? t1*t1 : 0.f);

    float S0 = block_sum(s0, red, tid);
    float Q0 = block_sum(q0, red, tid);
    float S1 = block_sum(s1, red, tid);
    float Q1 = block_sum(q1, red, tid);

    const float inv = 1.0f / 784.0f;
    float mu0 = S0 * inv, mu1 = S1 * inv;
    float rs0 = rsqrtf(Q0 * inv - mu0 * mu0 + 1e-5f);
    float rs1 = rsqrtf(Q1 * inv - mu1 * mu1 + 1e-5f);

    float* out0 = Vf + (b * 32 + o0) * 784;
    float* out1 = out0 + 784;
#pragma unroll
    for (int k = 0; k < 3; ++k) {
        int e = tid + 256 * k;
        out0[e] = act_sig_relu((a0[k] - mu0) * rs0);
        out1[e] = act_sig_relu((a1[k] - mu1) * rs1);
    }
    if (tail) {
        out0[tid + 768] = act_sig_relu((t0 - mu0) * rs0);
        out1[tid + 768] = act_sig_relu((t1 - mu1) * rs1);
    }
}

// ---------------------------------------------------------------------------
// Kernel 4: MFMA attention, transpose-free. S^T = K·Q^T (C: row=key, col=query)
// -> exp2 in-register -> bpermute re-grouping into PV B-frag (P^T) ->
// O^T = V'^T·P^T with ones-row rowsum. No P LDS strip: kt iterations are
// independent (ILP), no bank conflicts. V'^T A-frags hoisted (qt-invariant).
// ---------------------------------------------------------------------------
extern "C" __global__ __launch_bounds__(256) void attn_kernel(
    const unsigned short* __restrict__ Qb, const unsigned short* __restrict__ Kb,
    const float* __restrict__ Vf, const unsigned short* __restrict__ biasM,
    unsigned short* __restrict__ Ob)
{
    const int bh = blockIdx.x;
    const int b = bh >> 5, h = bh & 31;
    __shared__ alignas(16) unsigned short Qs[208][8];
    __shared__ alignas(16) unsigned short Ks[224][8];
    __shared__ alignas(16) unsigned short VT[16][232];
    const int tid = threadIdx.x;

    const unsigned short* Qrow = Qb + bh * 196 * 8;
    const unsigned short* Krow = Kb + bh * 196 * 8;
    if (tid < 208) {
        uint4 z = {0, 0, 0, 0};
        uint4 v = (tid < 196) ? *(const uint4*)(Qrow + tid * 8) : z;
        *(uint4*)&Qs[tid][0] = v;
    }
    if (tid < 224) {
        uint4 z = {0, 0, 0, 0};
        uint4 v = (tid < 196) ? *(const uint4*)(Krow + tid * 8) : z;
        *(uint4*)&Ks[tid][0] = v;
    }
    {
        unsigned int* vtw = (unsigned int*)&VT[0][0];
        for (int i = tid; i < (16 * 232) / 2; i += 256) vtw[i] = 0u;
    }
    __syncthreads();
    if (tid < 196) {
        float4 vv = *(const float4*)(Vf + bh * 784 + tid * 4);
        VT[0][tid] = f2u(vv.x); VT[1][tid] = f2u(vv.y);
        VT[2][tid] = f2u(vv.z); VT[3][tid] = f2u(vv.w);
        VT[4][tid] = 0x3F80;   // 1.0 bf16
    }
    __syncthreads();

    const int lane = tid & 63, wv = tid >> 6;
    const int quad = lane >> 4, tc = lane & 15;

    // Hoist V'^T A-frags (qt-invariant): A[m=d=tc][k=key=quad*8+j]
    bf16x8 vfr[7];
#pragma unroll
    for (int kt = 0; kt < 7; ++kt)
        vfr[kt] = *(const bf16x8*)&VT[tc][kt * 32 + quad * 8];

    // bpermute byte-addresses: dwords 0,1 from src lane 32*(q&1)+tc;
    // dwords 2,3 from +16. Tile select t=q>>1.
    const int srcA = ((quad & 1) * 32 + tc) * 4;
    const int srcB = srcA + 64;
    const bool useT1 = quad >= 2;

    const unsigned short* bias_hq0 = biasM + (h * 13) * 3584;

    for (int qt = wv; qt < 13; qt += 4) {
        // Q^T B-frag: real k-slice only in quad 0; others zero.
        bf16x8 bq = {};
        if (quad == 0) bq = *(const bf16x8*)&Qs[qt * 16 + tc][0];
        const unsigned short* bq_bias = bias_hq0 + qt * 3584;
        f32x4 Oacc = {};
#pragma unroll
        for (int kt = 0; kt < 7; ++kt) {
            // two S^T tiles: keys kt*32+{0..15}, {16..31} x 16 queries
            uint2 bw0 = *(const uint2*)(bq_bias + (kt * 2 + 0) * 256 + lane * 4);
            uint2 bw1 = *(const uint2*)(bq_bias + (kt * 2 + 1) * 256 + lane * 4);
            f32x4 s0, s1;
            {
                union { unsigned int u; float f; } c;
                c.u = bw0.x << 16;        s0[0] = c.f;
                c.u = bw0.x & 0xffff0000u; s0[1] = c.f;
                c.u = bw0.y << 16;        s0[2] = c.f;
                c.u = bw0.y & 0xffff0000u; s0[3] = c.f;
                c.u = bw1.x << 16;        s1[0] = c.f;
                c.u = bw1.x & 0xffff0000u; s1[1] = c.f;
                c.u = bw1.y << 16;        s1[2] = c.f;
                c.u = bw1.y & 0xffff0000u; s1[3] = c.f;
            }
            bf16x8 a0 = *(const bf16x8*)&Ks[(kt * 2 + 0) * 16 + tc][0];
            bf16x8 a1 = *(const bf16x8*)&Ks[(kt * 2 + 1) * 16 + tc][0];
            s0 = __builtin_amdgcn_mfma_f32_16x16x32_bf16(a0, bq, s0, 0, 0, 0);
            s1 = __builtin_amdgcn_mfma_f32_16x16x32_bf16(a1, bq, s1, 0, 0, 0);
            // P = exp2(S^T) per lane, pack row-pairs to bf16 dwords
            union { unsigned int u; __bf16 hh[2]; } t0d0, t0d1, t1d0, t1d1;
            t0d0.hh[0] = (__bf16)exp2f(s0[0]); t0d0.hh[1] = (__bf16)exp2f(s0[1]);
            t0d1.hh[0] = (__bf16)exp2f(s0[2]); t0d1.hh[1] = (__bf16)exp2f(s0[3]);
            t1d0.hh[0] = (__bf16)exp2f(s1[0]); t1d0.hh[1] = (__bf16)exp2f(s1[1]);
            t1d1.hh[0] = (__bf16)exp2f(s1[2]); t1d1.hh[1] = (__bf16)exp2f(s1[3]);
            // regroup into PV B-frag (P^T): key = quad*8+j
            int p0a = __builtin_amdgcn_ds_bpermute(srcA, (int)t0d0.u);
            int p0b = __builtin_amdgcn_ds_bpermute(srcA, (int)t1d0.u);
            int p1a = __builtin_amdgcn_ds_bpermute(srcA, (int)t0d1.u);
            int p1b = __builtin_amdgcn_ds_bpermute(srcA, (int)t1d1.u);
            int p2a = __builtin_amdgcn_ds_bpermute(srcB, (int)t0d0.u);
            int p2b = __builtin_amdgcn_ds_bpermute(srcB, (int)t1d0.u);
            int p3a = __builtin_amdgcn_ds_bpermute(srcB, (int)t0d1.u);
            int p3b = __builtin_amdgcn_ds_bpermute(srcB, (int)t1d1.u);
            union { int d[4]; bf16x8 v; } pf;
            pf.d[0] = useT1 ? p0b : p0a;
            pf.d[1] = useT1 ? p1b : p1a;
            pf.d[2] = useT1 ? p2b : p2a;
            pf.d[3] = useT1 ? p3b : p3a;
            Oacc = __builtin_amdgcn_mfma_f32_16x16x32_bf16(vfr[kt], pf.v, Oacc, 0, 0, 0);
        }
        // O^T C-frag: lane(q,tc): rows d=q*4+reg, col=query=tc.
        // quad0 holds d=0..3; quad1 reg0 holds d=4 = rowsum.
        float rs = __shfl(Oacc[0], 16 + tc);
        int q = qt * 16 + tc;
        if (quad == 0 && q < 196) {
            float inv = __builtin_amdgcn_rcpf(rs);
            union { uint2 v; unsigned short s[4]; } pk2;
            pk2.s[0] = f2u(Oacc[0] * inv);
            pk2.s[1] = f2u(Oacc[1] * inv);
            pk2.s[2] = f2u(Oacc[2] * inv);
            pk2.s[3] = f2u(Oacc[3] * inv);
            *(uint2*)&Ob[(b * 196 + q) * 128 + h * 4] = pk2.v;
        }
    }
}

// ---------------------------------------------------------------------------
// Kernel 5: output projection via MFMA bf16. out = Ob @ projW^T + b (fp32 out)
// ---------------------------------------------------------------------------
extern "C" __global__ __launch_bounds__(256) void proj_kernel(
    const unsigned short* __restrict__ Ob, const float* __restrict__ projw,
    const float* __restrict__ projb, float* __restrict__ out)
{
    __shared__ alignas(16) unsigned short AT[64][136];
    __shared__ alignas(16) unsigned short BT[64][136];
    const int tid = threadIdx.x;
    const int r0 = blockIdx.x * 64;
    const int j0 = blockIdx.y * 64;

    for (int idx = tid; idx < 1024; idx += 256) {
        int row = idx >> 4, k0 = (idx & 15) << 3;
        *(uint4*)&AT[row][k0] = *(const uint4*)&Ob[(r0 + row) * 128 + k0];
    }
    for (int idx = tid; idx < 2048; idx += 256) {
        int row = idx >> 5, k0 = (idx & 31) << 2;
        float4 v = *(const float4*)&projw[(j0 + row) * 128 + k0];
        ushort4 u; u.x = f2u(v.x); u.y = f2u(v.y); u.z = f2u(v.z); u.w = f2u(v.w);
        *(ushort4*)&BT[row][k0] = u;
    }
    __syncthreads();

    const int lane = tid & 63, w = tid >> 6;
    const int wm = (w >> 1) * 32, wn = (w & 1) * 32;
    const int quad = lane >> 4, tcol = lane & 15;

    f32x4 acc[2][2] = {};
#pragma unroll
    for (int ks = 0; ks < 4; ++ks) {
        int k0 = ks * 32 + quad * 8;
        bf16x8 a0 = *(const bf16x8*)&AT[wm + tcol][k0];
        bf16x8 a1 = *(const bf16x8*)&AT[wm + 16 + tcol][k0];
        bf16x8 b0 = *(const bf16x8*)&BT[wn + tcol][k0];
        bf16x8 b1 = *(const bf16x8*)&BT[wn + 16 + tcol][k0];
        acc[0][0] = __builtin_amdgcn_mfma_f32_16x16x32_bf16(a0, b0, acc[0][0], 0, 0, 0);
        acc[0][1] = __builtin_amdgcn_mfma_f32_16x16x32_bf16(a0, b1, acc[0][1], 0, 0, 0);
        acc[1][0] = __builtin_amdgcn_mfma_f32_16x16x32_bf16(a1, b0, acc[1][0], 0, 0, 0);
        acc[1][1] = __builtin_amdgcn_mfma_f32_16x16x32_bf16(a1, b1, acc[1][1], 0, 0, 0);
    }

#pragma unroll
    for (int mi = 0; mi < 2; ++mi) {
#pragma unroll
        for (int ni = 0; ni < 2; ++ni) {
            int j = j0 + wn + ni * 16 + tcol;
            float pb = projb[j];
#pragma unroll
            for (int reg = 0; reg < 4; ++reg) {
                int r = r0 + wm + mi * 16 + quad * 4 + reg;
                out[r * 128 + j] = acc[mi][ni][reg] + pb;
            }
        }
    }
}

// ---------------------------------------------------------------------------
extern "C" void kernel_launch(void* const* d_in, const int* in_sizes, int n_in,
                              void* d_out, int out_size, void* d_ws, size_t ws_size,
                              hipStream_t stream)
{
    const float* x1    = (const float*)d_in[0];
    const float* x2    = (const float*)d_in[1];
    const float* qkvw  = (const float*)d_in[2];
    const float* projw = (const float*)d_in[3];
    const float* projb = (const float*)d_in[4];
    const float* rpb   = (const float*)d_in[5];
    const float* fw    = (const float*)d_in[6];
    const float* fb    = (const float*)d_in[7];
    const int*   rel   = (const int*)d_in[8];
    float* out = (float*)d_out;

    char* w = (char*)d_ws;
    unsigned short* Qb  = (unsigned short*)(w);              //  6,422,528 B
    unsigned short* Kb  = (unsigned short*)(w + 6422528);    //  6,422,528 B
    unsigned short* V   = (unsigned short*)(w + 12845056);   //  6,422,528 B
    float*          Vf  = (float*)(w + 19267584);            //  6,422,528 B
    unsigned short* bM  = (unsigned short*)(w + 25690112);   //  2,981,888 B
    unsigned short* Ob  = (unsigned short*)(w + 28672000);   //  3,211,264 B

    qkv_gemm  <<<dim3(392, 6), dim3(256), 0, stream>>>(x1, x2, qkvw, Qb, Kb, V);
    bias_build<<<dim3(13, 32), dim3(256), 0, stream>>>(rel, rpb, bM);
    fuse_kernel<<<dim3(64, 16), dim3(256), 0, stream>>>(V, fw, fb, Vf);
    attn_kernel<<<dim3(2048),   dim3(256), 0, stream>>>(Qb, Kb, Vf, bM, Ob);
    proj_kernel<<<dim3(196, 2), dim3(256), 0, stream>>>(Ob, projw, projb, out);
}

// Round 6
// 153.729 us; speedup vs baseline: 1.2305x; 1.1320x over previous
//
#include <hip/hip_runtime.h>
#include <hip/hip_bf16.h>
#include <stdint.h>

// Problem constants
#define NB   64          // batch*windows
#define NTOK 196         // tokens per window
#define NH   32          // heads
#define HD   4           // head dim
#define CE   128         // embed
#define NM   38416       // 196*196

typedef __bf16 bf16x8 __attribute__((ext_vector_type(8)));
typedef short  bf16x4s __attribute__((ext_vector_type(4)));
typedef float  f32x4  __attribute__((ext_vector_type(4)));

#define QSCALE 0.7213475204444817f   /* 0.5 * log2(e) */
#define LOG2E  1.4426950408889634f

__device__ __forceinline__ float u2f(unsigned short u) {
    union { unsigned int i; float f; } z;
    z.i = ((unsigned int)u) << 16;
    return z.f;
}
__device__ __forceinline__ unsigned short f2u(float f) {
    union { float f; unsigned int i; } z; z.f = f;
    unsigned int x = z.i;
    return (unsigned short)((x + 0x7fffu + ((x >> 16) & 1u)) >> 16); // RNE
}

// ---------------------------------------------------------------------------
// Kernel 1: QKV GEMM (MFMA, C^T = W·X^T) + bias_build merged as grid.y==6.
// Qb/Kb packed bf16 [b,h][n][br*4+d] (Q pre-scaled), V bf16 [b][2H][n][d].
// bias: [h][qt 13][kt 7][lane 64][8 shorts] bf16*log2e, C-frag order of
// S^T tiles (row=key=quad*4+reg, col=query=tc); -inf in padding.
// ---------------------------------------------------------------------------
extern "C" __global__ __launch_bounds__(256) void qkv_bias(
    const float* __restrict__ x1,
    const float* __restrict__ x2,
    const float* __restrict__ qkvw,
    const int* __restrict__ rel_idx, const float* __restrict__ rpb,
    unsigned short* __restrict__ Qb, unsigned short* __restrict__ Kb,
    unsigned short* __restrict__ V, unsigned short* __restrict__ biasM)
{
    __shared__ alignas(16) unsigned short AT[64][136];   // X rows (tokens)
    __shared__ alignas(16) unsigned short BT[64][136];   // W rows (j)
    const int tid = threadIdx.x;

    if (blockIdx.y == 6) {
        // ---- bias path: 416 blocks = 13 qt x 32 h ----
        const int bx = blockIdx.x;
        const int qt = bx % 13, h = bx / 13;
        const int lane = tid & 63, wv = tid >> 6;
        const int quad = lane >> 4, tc = lane & 15;
        for (int nt = wv; nt < 14; nt += 4) {
            union { uint2 v; unsigned short s[4]; } e;
#pragma unroll
            for (int r = 0; r < 4; ++r) {
                int q   = qt * 16 + tc;              // query = col
                int key = nt * 16 + quad * 4 + r;    // key   = row
                unsigned short u = 0xFF80;           // -inf bf16
                if (q < 196 && key < 196) {
                    int idx = rel_idx[q * 196 + key];
                    u = f2u(rpb[idx * 32 + h] * LOG2E);
                }
                e.s[r] = u;
            }
            unsigned int off = (((h * 13 + qt) * 7 + (nt >> 1)) * 64 + lane) * 8
                               + (nt & 1) * 4;
            *(uint2*)(biasM + off) = e.v;
        }
        return;
    }
    if (blockIdx.x >= 392) return;

    const int r0 = blockIdx.x * 64;     // token rows (both branches stacked)
    const int j0 = blockIdx.y * 64;     // cols of 384

    for (int idx = tid; idx < 2048; idx += 256) {
        int row = idx >> 5, k0 = (idx & 31) << 2;
        int r = r0 + row;
        const float* xp = (r >= 12544) ? x2 : x1;
        int rem = r - ((r >= 12544) ? 12544 : 0);
        float4 v = *(const float4*)&xp[rem * 128 + k0];
        ushort4 u; u.x = f2u(v.x); u.y = f2u(v.y); u.z = f2u(v.z); u.w = f2u(v.w);
        *(ushort4*)&AT[row][k0] = u;
    }
    for (int idx = tid; idx < 2048; idx += 256) {
        int row = idx >> 5, k0 = (idx & 31) << 2;
        float4 v = *(const float4*)&qkvw[(j0 + row) * 128 + k0];
        ushort4 u; u.x = f2u(v.x); u.y = f2u(v.y); u.z = f2u(v.z); u.w = f2u(v.w);
        *(ushort4*)&BT[row][k0] = u;
    }
    __syncthreads();

    const int lane = tid & 63, w = tid >> 6;
    const int wj = (w >> 1) * 32;    // j offset (M dim)
    const int wt = (w & 1) * 32;     // token offset (N dim)
    const int quad = lane >> 4, tc = lane & 15;

    f32x4 acc[2][2] = {};
#pragma unroll
    for (int ks = 0; ks < 4; ++ks) {
        int k0 = ks * 32 + quad * 8;
        bf16x8 a0 = *(const bf16x8*)&BT[wj + tc][k0];
        bf16x8 a1 = *(const bf16x8*)&BT[wj + 16 + tc][k0];
        bf16x8 b0 = *(const bf16x8*)&AT[wt + tc][k0];
        bf16x8 b1 = *(const bf16x8*)&AT[wt + 16 + tc][k0];
        acc[0][0] = __builtin_amdgcn_mfma_f32_16x16x32_bf16(a0, b0, acc[0][0], 0, 0, 0);
        acc[0][1] = __builtin_amdgcn_mfma_f32_16x16x32_bf16(a0, b1, acc[0][1], 0, 0, 0);
        acc[1][0] = __builtin_amdgcn_mfma_f32_16x16x32_bf16(a1, b0, acc[1][0], 0, 0, 0);
        acc[1][1] = __builtin_amdgcn_mfma_f32_16x16x32_bf16(a1, b1, acc[1][1], 0, 0, 0);
    }

    const int sel = j0 >> 7;   // 0=q 1=k 2=v, uniform per block
#pragma unroll
    for (int mi = 0; mi < 2; ++mi) {
        int jbase = (j0 + wj + mi * 16 + quad * 4) & 127;
        int hh = jbase >> 2;
#pragma unroll
        for (int ni = 0; ni < 2; ++ni) {
            int tok = r0 + wt + ni * 16 + tc;
            int branch = (tok >= 12544) ? 1 : 0;
            int rem = tok - branch * 12544;
            int bb = rem / 196;
            int nn = rem - bb * 196;
            union { uint2 v; unsigned short s[4]; } pk2;
            if (sel == 0) {
#pragma unroll
                for (int r = 0; r < 4; ++r) pk2.s[r] = f2u(acc[mi][ni][r] * QSCALE);
                *(uint2*)&Qb[((bb * 32 + hh) * 196 + nn) * 8 + branch * 4] = pk2.v;
            } else if (sel == 1) {
#pragma unroll
                for (int r = 0; r < 4; ++r) pk2.s[r] = f2u(acc[mi][ni][r]);
                *(uint2*)&Kb[((bb * 32 + hh) * 196 + nn) * 8 + branch * 4] = pk2.v;
            } else {
#pragma unroll
                for (int r = 0; r < 4; ++r) pk2.s[r] = f2u(acc[mi][ni][r]);
                *(uint2*)&V[(bb * 64 + branch * 32 + hh) * 784 + nn * 4] = pk2.v;
            }
        }
    }
}

// ---------------------------------------------------------------------------
// Kernel 2: conv-gated value fusion + InstanceNorm + sigmoid(relu). (unchanged)
// ---------------------------------------------------------------------------
__device__ __forceinline__ float block_sum(float v, float* red, int tid) {
#pragma unroll
    for (int off = 32; off > 0; off >>= 1) v += __shfl_down(v, off);
    __syncthreads();
    if ((tid & 63) == 0) red[tid >> 6] = v;
    __syncthreads();
    return red[0] + red[1] + red[2] + red[3];
}

__device__ __forceinline__ float act_sig_relu(float x) {
    return x > 0.f ? __fdividef(1.f, 1.f + __expf(-x)) : 0.5f;
}

extern "C" __global__ __launch_bounds__(256) void fuse_kernel(
    const unsigned short* __restrict__ V,
    const float* __restrict__ fuse_w,
    const float* __restrict__ fuse_b,
    float* __restrict__ Vf)
{
    const int b = blockIdx.x, o0 = blockIdx.y * 2;
    const int tid = threadIdx.x;
    __shared__ float fws[2][64];
    __shared__ float red[4];
    if (tid < 128) fws[tid >> 6][tid & 63] = fuse_w[(o0 + (tid >> 6)) * 64 + (tid & 63)];
    __syncthreads();

    const unsigned short* Vb = V + b * 64 * 784;
    float a0[3] = {0.f, 0.f, 0.f}, a1[3] = {0.f, 0.f, 0.f};
    float t0 = 0.f, t1 = 0.f;
    const bool tail = tid < 16;
    for (int c = 0; c < 64; ++c) {
        float w0 = fws[0][c], w1 = fws[1][c];
        const unsigned short* Vc = Vb + c * 784;
#pragma unroll
        for (int k = 0; k < 3; ++k) {
            float x = u2f(Vc[tid + 256 * k]);
            a0[k] = fmaf(w0, x, a0[k]);
            a1[k] = fmaf(w1, x, a1[k]);
        }
        if (tail) {
            float x = u2f(Vc[tid + 768]);
            t0 = fmaf(w0, x, t0);
            t1 = fmaf(w1, x, t1);
        }
    }
    float fb0 = fuse_b[o0], fb1 = fuse_b[o0 + 1];
#pragma unroll
    for (int k = 0; k < 3; ++k) { a0[k] += fb0; a1[k] += fb1; }
    t0 += fb0; t1 += fb1;

    float s0 = a0[0] + a0[1] + a0[2] + (tail ? t0 : 0.f);
    float q0 = a0[0]*a0[0] + a0[1]*a0[1] + a0[2]*a0[2] + (tail ? t0*t0 : 0.f);
    float s1 = a1[0] + a1[1] + a1[2] + (tail ? t1 : 0.f);
    float q1 = a1[0]*a1[0] + a1[1]*a1[1] + a1[2]*a1[2] + (tail ? t1*t1 : 0.f);

    float S0 = block_sum(s0, red, tid);
    float Q0 = block_sum(q0, red, tid);
    float S1 = block_sum(s1, red, tid);
    float Q1 = block_sum(q1, red, tid);

    const float inv = 1.0f / 784.0f;
    float mu0 = S0 * inv, mu1 = S1 * inv;
    float rs0 = rsqrtf(Q0 * inv - mu0 * mu0 + 1e-5f);
    float rs1 = rsqrtf(Q1 * inv - mu1 * mu1 + 1e-5f);

    float* out0 = Vf + (b * 32 + o0) * 784;
    float* out1 = out0 + 784;
#pragma unroll
    for (int k = 0; k < 3; ++k) {
        int e = tid + 256 * k;
        out0[e] = act_sig_relu((a0[k] - mu0) * rs0);
        out1[e] = act_sig_relu((a1[k] - mu1) * rs1);
    }
    if (tail) {
        out0[tid + 768] = act_sig_relu((t0 - mu0) * rs0);
        out1[tid + 768] = act_sig_relu((t1 - mu1) * rs1);
    }
}

// ---------------------------------------------------------------------------
// Kernel 3: MFMA attention, permute-free. S^T = K·Q^T via 16x16x32 (bias as
// C-init, single uint4 load). exp2 in-register, v_perm truncation-pack to
// bf16 pairs -> the 16x16x16 B-frag layout is IDENTICAL to the C-frag layout
// -> PV = mfma_f32_16x16x16bf16_1k directly, no bpermute/LDS round-trip.
// O^T = V'^T·P^T with ones-row rowsum; V'^T A-frags (b64) hoisted.
// ---------------------------------------------------------------------------
extern "C" __global__ __launch_bounds__(256) void attn_kernel(
    const unsigned short* __restrict__ Qb, const unsigned short* __restrict__ Kb,
    const float* __restrict__ Vf, const unsigned short* __restrict__ biasM,
    unsigned short* __restrict__ Ob)
{
    const int bh = blockIdx.x;
    const int b = bh >> 5, h = bh & 31;
    __shared__ alignas(16) unsigned short Qs[208][8];
    __shared__ alignas(16) unsigned short Ks[224][8];
    __shared__ alignas(16) unsigned short VT[16][232];
    const int tid = threadIdx.x;

    const unsigned short* Qrow = Qb + bh * 196 * 8;
    const unsigned short* Krow = Kb + bh * 196 * 8;
    if (tid < 208) {
        uint4 z = {0, 0, 0, 0};
        uint4 v = (tid < 196) ? *(const uint4*)(Qrow + tid * 8) : z;
        *(uint4*)&Qs[tid][0] = v;
    }
    if (tid < 224) {
        uint4 z = {0, 0, 0, 0};
        uint4 v = (tid < 196) ? *(const uint4*)(Krow + tid * 8) : z;
        *(uint4*)&Ks[tid][0] = v;
    }
    {
        unsigned int* vtw = (unsigned int*)&VT[0][0];
        for (int i = tid; i < (16 * 232) / 2; i += 256) vtw[i] = 0u;
    }
    __syncthreads();
    if (tid < 196) {
        float4 vv = *(const float4*)(Vf + bh * 784 + tid * 4);
        VT[0][tid] = f2u(vv.x); VT[1][tid] = f2u(vv.y);
        VT[2][tid] = f2u(vv.z); VT[3][tid] = f2u(vv.w);
        VT[4][tid] = 0x3F80;   // 1.0 bf16
    }
    __syncthreads();

    const int lane = tid & 63, wv = tid >> 6;
    const int quad = lane >> 4, tc = lane & 15;

    // Hoist V'^T 16x16x16 A-frags (qt-invariant): A[m=tc][k=quad*4+j], tile t
    bf16x4s vfr16[14];
#pragma unroll
    for (int t = 0; t < 14; ++t)
        vfr16[t] = *(const bf16x4s*)&VT[tc][t * 16 + quad * 4];

    const unsigned short* bias_h = biasM + (unsigned)(h * 13) * 3584;

    for (int qt = wv; qt < 13; qt += 4) {
        bf16x8 bq = {};
        if (quad == 0) bq = *(const bf16x8*)&Qs[qt * 16 + tc][0];
        const unsigned short* bias_q = bias_h + qt * 3584;
        f32x4 Oacc = {};
#pragma unroll
        for (int kt = 0; kt < 7; ++kt) {
            uint4 bw = *(const uint4*)(bias_q + kt * 512 + lane * 8);
            f32x4 s0, s1;
            {
                union { unsigned int u; float f; } c;
                c.u = bw.x << 16;          s0[0] = c.f;
                c.u = bw.x & 0xffff0000u;  s0[1] = c.f;
                c.u = bw.y << 16;          s0[2] = c.f;
                c.u = bw.y & 0xffff0000u;  s0[3] = c.f;
                c.u = bw.z << 16;          s1[0] = c.f;
                c.u = bw.z & 0xffff0000u;  s1[1] = c.f;
                c.u = bw.w << 16;          s1[2] = c.f;
                c.u = bw.w & 0xffff0000u;  s1[3] = c.f;
            }
            bf16x8 a0 = *(const bf16x8*)&Ks[(kt * 2 + 0) * 16 + tc][0];
            bf16x8 a1 = *(const bf16x8*)&Ks[(kt * 2 + 1) * 16 + tc][0];
            s0 = __builtin_amdgcn_mfma_f32_16x16x32_bf16(a0, bq, s0, 0, 0, 0);
            s1 = __builtin_amdgcn_mfma_f32_16x16x32_bf16(a1, bq, s1, 0, 0, 0);
            // P = exp2(S^T); truncation-pack pairs to bf16 (P>=0, softmax
            // renormalizes, so trunc error largely cancels).
            float e0 = __builtin_amdgcn_exp2f(s0[0]);
            float e1 = __builtin_amdgcn_exp2f(s0[1]);
            float e2 = __builtin_amdgcn_exp2f(s0[2]);
            float e3 = __builtin_amdgcn_exp2f(s0[3]);
            float g0 = __builtin_amdgcn_exp2f(s1[0]);
            float g1 = __builtin_amdgcn_exp2f(s1[1]);
            float g2 = __builtin_amdgcn_exp2f(s1[2]);
            float g3 = __builtin_amdgcn_exp2f(s1[3]);
            union { int d[2]; bf16x4s v; } pf0, pf1;
            pf0.d[0] = (int)__builtin_amdgcn_perm(__float_as_uint(e1), __float_as_uint(e0), 0x07060302u);
            pf0.d[1] = (int)__builtin_amdgcn_perm(__float_as_uint(e3), __float_as_uint(e2), 0x07060302u);
            pf1.d[0] = (int)__builtin_amdgcn_perm(__float_as_uint(g1), __float_as_uint(g0), 0x07060302u);
            pf1.d[1] = (int)__builtin_amdgcn_perm(__float_as_uint(g3), __float_as_uint(g2), 0x07060302u);
            Oacc = __builtin_amdgcn_mfma_f32_16x16x16bf16_1k(vfr16[kt * 2 + 0], pf0.v, Oacc, 0, 0, 0);
            Oacc = __builtin_amdgcn_mfma_f32_16x16x16bf16_1k(vfr16[kt * 2 + 1], pf1.v, Oacc, 0, 0, 0);
        }
        // O^T C-frag: rows d=quad*4+reg, col=query=tc. Rowsum = row 4
        // (quad 1, reg 0); quad 0 holds d=0..3.
        float rs = __shfl(Oacc[0], 16 + tc);
        int q = qt * 16 + tc;
        if (quad == 0 && q < 196) {
            float inv = __builtin_amdgcn_rcpf(rs);
            union { uint2 v; unsigned short s[4]; } pk2;
            pk2.s[0] = f2u(Oacc[0] * inv);
            pk2.s[1] = f2u(Oacc[1] * inv);
            pk2.s[2] = f2u(Oacc[2] * inv);
            pk2.s[3] = f2u(Oacc[3] * inv);
            *(uint2*)&Ob[(b * 196 + q) * 128 + h * 4] = pk2.v;
        }
    }
}

// ---------------------------------------------------------------------------
// Kernel 4: output projection via MFMA bf16. out = Ob @ projW^T + b (fp32 out)
// ---------------------------------------------------------------------------
extern "C" __global__ __launch_bounds__(256) void proj_kernel(
    const unsigned short* __restrict__ Ob, const float* __restrict__ projw,
    const float* __restrict__ projb, float* __restrict__ out)
{
    __shared__ alignas(16) unsigned short AT[64][136];
    __shared__ alignas(16) unsigned short BT[64][136];
    const int tid = threadIdx.x;
    const int r0 = blockIdx.x * 64;
    const int j0 = blockIdx.y * 64;

    for (int idx = tid; idx < 1024; idx += 256) {
        int row = idx >> 4, k0 = (idx & 15) << 3;
        *(uint4*)&AT[row][k0] = *(const uint4*)&Ob[(r0 + row) * 128 + k0];
    }
    for (int idx = tid; idx < 2048; idx += 256) {
        int row = idx >> 5, k0 = (idx & 31) << 2;
        float4 v = *(const float4*)&projw[(j0 + row) * 128 + k0];
        ushort4 u; u.x = f2u(v.x); u.y = f2u(v.y); u.z = f2u(v.z); u.w = f2u(v.w);
        *(ushort4*)&BT[row][k0] = u;
    }
    __syncthreads();

    const int lane = tid & 63, w = tid >> 6;
    const int wm = (w >> 1) * 32, wn = (w & 1) * 32;
    const int quad = lane >> 4, tcol = lane & 15;

    f32x4 acc[2][2] = {};
#pragma unroll
    for (int ks = 0; ks < 4; ++ks) {
        int k0 = ks * 32 + quad * 8;
        bf16x8 a0 = *(const bf16x8*)&AT[wm + tcol][k0];
        bf16x8 a1 = *(const bf16x8*)&AT[wm + 16 + tcol][k0];
        bf16x8 b0 = *(const bf16x8*)&BT[wn + tcol][k0];
        bf16x8 b1 = *(const bf16x8*)&BT[wn + 16 + tcol][k0];
        acc[0][0] = __builtin_amdgcn_mfma_f32_16x16x32_bf16(a0, b0, acc[0][0], 0, 0, 0);
        acc[0][1] = __builtin_amdgcn_mfma_f32_16x16x32_bf16(a0, b1, acc[0][1], 0, 0, 0);
        acc[1][0] = __builtin_amdgcn_mfma_f32_16x16x32_bf16(a1, b0, acc[1][0], 0, 0, 0);
        acc[1][1] = __builtin_amdgcn_mfma_f32_16x16x32_bf16(a1, b1, acc[1][1], 0, 0, 0);
    }

#pragma unroll
    for (int mi = 0; mi < 2; ++mi) {
#pragma unroll
        for (int ni = 0; ni < 2; ++ni) {
            int j = j0 + wn + ni * 16 + tcol;
            float pb = projb[j];
#pragma unroll
            for (int reg = 0; reg < 4; ++reg) {
                int r = r0 + wm + mi * 16 + quad * 4 + reg;
                out[r * 128 + j] = acc[mi][ni][reg] + pb;
            }
        }
    }
}

// ---------------------------------------------------------------------------
extern "C" void kernel_launch(void* const* d_in, const int* in_sizes, int n_in,
                              void* d_out, int out_size, void* d_ws, size_t ws_size,
                              hipStream_t stream)
{
    const float* x1    = (const float*)d_in[0];
    const float* x2    = (const float*)d_in[1];
    const float* qkvw  = (const float*)d_in[2];
    const float* projw = (const float*)d_in[3];
    const float* projb = (const float*)d_in[4];
    const float* rpb   = (const float*)d_in[5];
    const float* fw    = (const float*)d_in[6];
    const float* fb    = (const float*)d_in[7];
    const int*   rel   = (const int*)d_in[8];
    float* out = (float*)d_out;

    char* w = (char*)d_ws;
    unsigned short* Qb  = (unsigned short*)(w);              //  6,422,528 B
    unsigned short* Kb  = (unsigned short*)(w + 6422528);    //  6,422,528 B
    unsigned short* V   = (unsigned short*)(w + 12845056);   //  6,422,528 B
    float*          Vf  = (float*)(w + 19267584);            //  6,422,528 B
    unsigned short* bM  = (unsigned short*)(w + 25690112);   //  2,981,888 B
    unsigned short* Ob  = (unsigned short*)(w + 28672000);   //  3,211,264 B

    qkv_bias  <<<dim3(416, 7), dim3(256), 0, stream>>>(x1, x2, qkvw, rel, rpb,
                                                       Qb, Kb, V, bM);
    fuse_kernel<<<dim3(64, 16), dim3(256), 0, stream>>>(V, fw, fb, Vf);
    attn_kernel<<<dim3(2048),   dim3(256), 0, stream>>>(Qb, Kb, Vf, bM, Ob);
    proj_kernel<<<dim3(196, 2), dim3(256), 0, stream>>>(Ob, projw, projb, out);
}